// Round 4
// baseline (451.609 us; speedup 1.0000x reference)
//
#include <hip/hip_runtime.h>
#include <hip/hip_bf16.h>
#include <stdint.h>

#define NN 50000
#define NE 400000
#define DD 256
#define MPAD 50048   /* 391*128 */
#define EPSV 1e-5f

typedef __attribute__((ext_vector_type(8))) short bf16x8;
typedef __attribute__((ext_vector_type(8))) unsigned short u16x8;
typedef __attribute__((ext_vector_type(4))) float f32x4;

static __device__ __forceinline__ float bf2f(unsigned short u){
  union{unsigned int i; float f;} x; x.i=((unsigned int)u)<<16; return x.f;
}
static __device__ __forceinline__ unsigned short f2bf(float f){
  union{float f; unsigned int i;} x; x.f=f;
  return (unsigned short)((x.i + 0x7FFFu + ((x.i>>16)&1u))>>16);
}
static __device__ __forceinline__ void gl_lds16(const void* g, void* l){
  __builtin_amdgcn_global_load_lds((const __attribute__((address_space(1))) void*)g,
                                   (__attribute__((address_space(3))) void*)l, 16, 0, 0);
}

/* ---------------- graph preprocessing ---------------- */

__global__ void k_degree(const int* __restrict__ ei, int* __restrict__ degi_out,
                         int* __restrict__ degi_in){
  int e = blockIdx.x*256 + threadIdx.x;
  if(e < NE){
    atomicAdd(&degi_out[ei[e]], 1);
    atomicAdd(&degi_in[ei[NE + e]], 1);
  }
}

__global__ void k_dscale(const int* __restrict__ degi_out, const int* __restrict__ degi_in,
                         float* __restrict__ dso, float* __restrict__ dsi){
  int n = blockIdx.x*256 + threadIdx.x;
  if(n < NN){
    dso[n] = rsqrtf((float)max(degi_out[n],1));
    dsi[n] = rsqrtf((float)max(degi_in[n],1));
  }
}

/* single-block exclusive scan over in-degrees -> rowptr, cursor */
__global__ void k_scan(const int* __restrict__ cnt, int* __restrict__ rowptr,
                       int* __restrict__ cursor, int n){
  __shared__ int wsum[16];
  __shared__ int s_carry;
  int tid = threadIdx.x, lane = tid & 63, wv = tid >> 6;
  if(tid==0) s_carry = 0;
  __syncthreads();
  for(int base=0; base<n; base+=1024){
    int i = base + tid;
    int v = (i<n) ? cnt[i] : 0;
    int sc = v;
    for(int off=1; off<64; off<<=1){
      int t = __shfl_up(sc, off);
      if(lane >= off) sc += t;
    }
    if(lane==63) wsum[wv] = sc;
    __syncthreads();
    if(wv==0){
      int t = (lane<16) ? wsum[lane] : 0;
      for(int off=1; off<16; off<<=1){
        int u = __shfl_up(t, off);
        if(lane >= off) t += u;
      }
      if(lane<16) wsum[lane] = t;   /* inclusive prefix of wave totals */
    }
    __syncthreads();
    int woff = (wv==0) ? 0 : wsum[wv-1];
    int carry = s_carry;
    int ex = carry + woff + sc - v;
    if(i<n){ rowptr[i] = ex; cursor[i] = ex; }
    __syncthreads();
    if(tid==0) s_carry = carry + wsum[15];
    __syncthreads();
  }
  if(tid==0) rowptr[n] = s_carry;
}

__global__ void k_fill(const int* __restrict__ ei, int* __restrict__ cursor,
                       int* __restrict__ eidx){
  int e = blockIdx.x*256 + threadIdx.x;
  if(e < NE){
    int c = ei[NE + e];
    int p = atomicAdd(&cursor[c], 1);
    eidx[p] = ei[e];
  }
}

/* all 3 layers: W [K][Ncol] f32 -> Wt [Ncol][K] bf16 */
__global__ void k_convw(const float* __restrict__ W0, const float* __restrict__ W1,
                        const float* __restrict__ W2, unsigned short* __restrict__ Wt){
  int t = blockIdx.x*256 + threadIdx.x;   /* 3*65536 */
  int l = t >> 16, r = t & 65535;
  int k = r >> 8, n = r & 255;
  const float* W = (l==0) ? W0 : (l==1) ? W1 : W2;
  Wt[(size_t)l*65536 + n*256 + k] = f2bf(W[k*256 + n]);
}

/* hs = x * dso[row], bf16 */
__global__ void k_prep0(const float* __restrict__ x, const float* __restrict__ dso,
                        unsigned short* __restrict__ hs){
  int t = blockIdx.x*256 + threadIdx.x;   /* NN*64 */
  int row = t >> 6, c4 = (t & 63) << 2;
  if(row < NN){
    float s = dso[row];
    float4 v = *(const float4*)(x + (size_t)row*256 + c4);
    ushort4 o;
    o.x = f2bf(v.x*s); o.y = f2bf(v.y*s); o.z = f2bf(v.z*s); o.w = f2bf(v.w*s);
    *(ushort4*)(hs + (size_t)row*256 + c4) = o;
  }
}

/* one wave per destination node; index broadcast + 4 independent 16B gathers
   in flight per half-wave */
__global__ void k_agg(const unsigned short* __restrict__ hs, const int* __restrict__ rowptr,
                      const int* __restrict__ eidx, unsigned short* __restrict__ agg){
  int node = blockIdx.x*4 + (threadIdx.x >> 6);
  int lane = threadIdx.x & 63;
  int pair = lane >> 5, l32 = lane & 31;
  float a[8] = {0.f,0.f,0.f,0.f,0.f,0.f,0.f,0.f};
  int s = 0, e = 0;
  if(node < NN){ s = rowptr[node]; e = rowptr[node+1]; }
  int deg = e - s;
  for(int base=0; base<deg; base+=64){
    int cnt = min(deg - base, 64);
    int myidx = (base + lane < deg) ? eidx[s + base + lane] : 0;
    for(int g=0; g<cnt; g+=8){
      int jb = g + pair*4;
      int s0 = __shfl(myidx, jb+0);
      int s1 = __shfl(myidx, jb+1);
      int s2 = __shfl(myidx, jb+2);
      int s3 = __shfl(myidx, jb+3);
      u16x8 v0 = *(const u16x8*)(hs + (size_t)s0*256 + l32*8);
      u16x8 v1 = *(const u16x8*)(hs + (size_t)s1*256 + l32*8);
      u16x8 v2 = *(const u16x8*)(hs + (size_t)s2*256 + l32*8);
      u16x8 v3 = *(const u16x8*)(hs + (size_t)s3*256 + l32*8);
      if(jb+0 < cnt){
        #pragma unroll
        for(int k2=0;k2<8;k2++) a[k2] += bf2f(v0[k2]);
      }
      if(jb+1 < cnt){
        #pragma unroll
        for(int k2=0;k2<8;k2++) a[k2] += bf2f(v1[k2]);
      }
      if(jb+2 < cnt){
        #pragma unroll
        for(int k2=0;k2<8;k2++) a[k2] += bf2f(v2[k2]);
      }
      if(jb+3 < cnt){
        #pragma unroll
        for(int k2=0;k2<8;k2++) a[k2] += bf2f(v3[k2]);
      }
    }
  }
  #pragma unroll
  for(int k2=0;k2<8;k2++) a[k2] += __shfl_xor(a[k2], 32);
  if(pair==0 && node < MPAD){
    u16x8 o;
    #pragma unroll
    for(int k2=0;k2<8;k2++) o[k2] = f2bf(a[k2]);
    *(u16x8*)(agg + (size_t)node*256 + l32*8) = o;
  }
}

/* GEMM: out[m][n] = (sum_k A[m][k]*W[k][n] + b[n]) * dsi[m] (+ residual).
   Double-buffered staging (2-phase): STAGE(next) || compute(cur), one
   vmcnt(0)+barrier per K-step. No stats, no atomics.
   RESMODE: 0=none, 1=f32 residual, 2=bf16 residual. OUTBF: bf16 vs f32 out. */
template<int RESMODE, int OUTBF>
__global__ __launch_bounds__(256) void k_gemm(
    const unsigned short* __restrict__ A,    /* [MPAD][256] bf16 */
    const unsigned short* __restrict__ Bt,   /* [256][256] bf16 = W^T */
    const float* __restrict__ bias,
    const float* __restrict__ dsi,
    const float* __restrict__ resf,
    const unsigned short* __restrict__ resb,
    void* __restrict__ outp)
{
  __shared__ __align__(16) unsigned char smem[65536];   /* 2 x (16KB A + 16KB B) */
  const int tid = threadIdx.x;
  const int w = tid >> 6, lane = tid & 63;
  const int m0 = blockIdx.x * 128, n0 = blockIdx.y * 128;
  const int wm = w >> 1, wn = w & 1;

  f32x4 acc[4][4];
  #pragma unroll
  for(int i=0;i<4;i++)
    #pragma unroll
    for(int j=0;j<4;j++) acc[i][j] = (f32x4){0.f,0.f,0.f,0.f};

  const char* Ab = (const char*)A;
  const char* Bb = (const char*)Bt;

  auto STAGE = [&](int buf, int kt){
    unsigned char* sA = smem + buf*32768;
    unsigned char* sB = sA + 16384;
    #pragma unroll
    for(int it=0; it<4; ++it){
      const int flat = w*256 + it*64 + lane;
      const int row = flat >> 3;
      const int ch  = flat & 7;
      const int sw  = ch ^ (row & 7);            /* pre-swizzled global source */
      gl_lds16(Ab + (size_t)(m0+row)*512 + kt*128 + sw*16,
               sA + (size_t)(w*256 + it*64)*16);
      gl_lds16(Bb + (size_t)(n0+row)*512 + kt*128 + sw*16,
               sB + (size_t)(w*256 + it*64)*16);
    }
  };

  STAGE(0, 0);
  asm volatile("s_waitcnt vmcnt(0)");
  __builtin_amdgcn_s_barrier();

  for(int kt=0; kt<4; ++kt){
    const int cur = kt & 1;
    if(kt < 3) STAGE(cur^1, kt+1);
    unsigned char* sA = smem + cur*32768;
    unsigned char* sB = sA + 16384;
    #pragma unroll
    for(int ks=0; ks<2; ++ks){
      bf16x8 av[4], bv[4];
      #pragma unroll
      for(int f=0; f<4; ++f){
        const int ra = wm*64 + f*16 + (lane & 15);
        const int ca = ks*4 + (lane >> 4);
        av[f] = *(const bf16x8*)(sA + ra*128 + ((ca ^ (ra & 7)) << 4));
        const int rb = wn*64 + f*16 + (lane & 15);
        bv[f] = *(const bf16x8*)(sB + rb*128 + ((ca ^ (rb & 7)) << 4));
      }
      #pragma unroll
      for(int mf=0; mf<4; ++mf)
        #pragma unroll
        for(int nf=0; nf<4; ++nf)
          acc[mf][nf] = __builtin_amdgcn_mfma_f32_16x16x32_bf16(av[mf], bv[nf], acc[mf][nf], 0,0,0);
    }
    asm volatile("s_waitcnt vmcnt(0)");   /* next-tile loads landed (overlapped w/ MFMA) */
    __builtin_amdgcn_s_barrier();
  }

  /* epilogue: C row = (lane>>4)*4+j, col = lane&15 (per 16x16 frag).
     Residual batched per mf-frag (16 loads in flight). */
  const int colb = n0 + wn*64 + (lane & 15);
  float bs[4];
  #pragma unroll
  for(int nf=0; nf<4; ++nf) bs[nf] = bias[colb + nf*16];
  #pragma unroll
  for(int mf=0; mf<4; ++mf){
    const int growb = m0 + wm*64 + mf*16 + ((lane>>4)<<2);
    float rv[16];
    if(RESMODE){
      #pragma unroll
      for(int j=0; j<4; ++j){
        const int grow = growb + j;
        if(grow < NN){
          const size_t rb = (size_t)grow * 256;
          #pragma unroll
          for(int nf=0; nf<4; ++nf)
            rv[j*4+nf] = (RESMODE==1) ? resf[rb + colb + nf*16]
                                      : bf2f(resb[rb + colb + nf*16]);
        }
      }
    }
    #pragma unroll
    for(int j=0; j<4; ++j){
      const int grow = growb + j;
      if(grow < NN){
        const float d = dsi[grow];
        const size_t rb = (size_t)grow * 256;
        #pragma unroll
        for(int nf=0; nf<4; ++nf){
          float v = (acc[mf][nf][j] + bs[nf]) * d;
          if(RESMODE) v += rv[j*4+nf];
          if(OUTBF) ((unsigned short*)outp)[rb + colb + nf*16] = f2bf(v);
          else      ((float*)outp)[rb + colb + nf*16] = v;
        }
      }
    }
  }
}

/* two-stage column stats: 256 blocks x 256 cols partial sums (no atomics) */
__global__ void k_stats(const unsigned short* __restrict__ ob,
                        float* __restrict__ ps, float* __restrict__ pq){
  int c = threadIdx.x, b = blockIdx.x;
  float s = 0.f, q = 0.f;
  for(int r = b; r < NN; r += 256){
    float v = bf2f(ob[(size_t)r*256 + c]);
    s += v; q += v*v;
  }
  ps[b*256 + c] = s;
  pq[b*256 + c] = q;
}

__global__ void k_statsfin2(const float* __restrict__ ps, const float* __restrict__ pq,
                            const float* __restrict__ g, const float* __restrict__ be,
                            float* __restrict__ cscale, float* __restrict__ cshift){
  int c = threadIdx.x;
  float s = 0.f, q = 0.f;
  for(int b = 0; b < 256; ++b){ s += ps[b*256 + c]; q += pq[b*256 + c]; }
  float mu  = s * (1.0f/NN);
  float var = q * (1.0f/NN) - mu*mu;
  var = fmaxf(var, 0.f);
  float inv = rsqrtf(var + EPSV);
  float sc = g[c] * inv;
  cscale[c] = sc;
  cshift[c] = be[c] - mu * sc;
}

/* y = relu(ob*cscale+cshift); optionally keep bf16 h (residual for next layer);
   always emit bf16 y*dso (next gather source) */
template<int WRITE_H>
__global__ void k_norm(const unsigned short* __restrict__ ob, const float* __restrict__ cscale,
                       const float* __restrict__ cshift, const float* __restrict__ dso,
                       unsigned short* __restrict__ h1, unsigned short* __restrict__ hs){
  int t = blockIdx.x*256 + threadIdx.x;   /* NN*32 */
  int row = t >> 5, c8 = (t & 31) << 3;
  if(row >= NN) return;
  u16x8 v = *(const u16x8*)(ob + (size_t)row*256 + c8);
  float s = dso[row];
  u16x8 oh, os;
  #pragma unroll
  for(int k2=0;k2<8;k2++){
    float y = fmaxf(bf2f(v[k2])*cscale[c8+k2] + cshift[c8+k2], 0.f);
    oh[k2] = f2bf(y);
    os[k2] = f2bf(y*s);
  }
  if(WRITE_H) *(u16x8*)(h1 + (size_t)row*256 + c8) = oh;
  *(u16x8*)(hs + (size_t)row*256 + c8) = os;
}

extern "C" void kernel_launch(void* const* d_in, const int* in_sizes, int n_in,
                              void* d_out, int out_size, void* d_ws, size_t ws_size,
                              hipStream_t stream){
  (void)in_sizes; (void)n_in; (void)out_size;
  const float* x  = (const float*)d_in[0];
  const int*   ei = (const int*)d_in[1];
  const float* Wl[3]  = {(const float*)d_in[2], (const float*)d_in[6], (const float*)d_in[10]};
  const float* bl[3]  = {(const float*)d_in[3], (const float*)d_in[7], (const float*)d_in[11]};
  const float* gl[2]  = {(const float*)d_in[4], (const float*)d_in[8]};
  const float* bel[2] = {(const float*)d_in[5], (const float*)d_in[9]};

  char* base = (char*)d_ws;
  size_t off = 0;
  auto alloc = [&](size_t bytes)->char* {
    char* r = base + off;
    off = (off + bytes + 511) & ~(size_t)511;
    return r;
  };
  int* degi_out = (int*)alloc((size_t)2*NN*4);
  int* degi_in  = degi_out + NN;
  float* dso    = (float*)alloc((size_t)NN*4);
  float* dsi    = (float*)alloc((size_t)NN*4);
  int* rowptr   = (int*)alloc((size_t)(NN+1)*4);
  int* cursor   = (int*)alloc((size_t)NN*4);
  int* eidx     = (int*)alloc((size_t)NE*4);
  unsigned short* Wt = (unsigned short*)alloc((size_t)3*65536*2);
  float* ps     = (float*)alloc((size_t)256*256*4);
  float* pq     = (float*)alloc((size_t)256*256*4);
  float* cscale = (float*)alloc(1024);
  float* cshift = (float*)alloc(1024);
  unsigned short* hs  = (unsigned short*)alloc((size_t)MPAD*256*2);
  unsigned short* agg = (unsigned short*)alloc((size_t)MPAD*256*2);
  unsigned short* h1  = (unsigned short*)alloc((size_t)MPAD*256*2);
  unsigned short* ob  = (unsigned short*)alloc((size_t)MPAD*256*2);
  if(off > ws_size) return;   /* workspace too small: fail visibly */

  /* graph prep (layer-invariant) */
  hipMemsetAsync(degi_out, 0, (size_t)2*NN*4, stream);
  k_degree<<<(NE+255)/256, 256, 0, stream>>>(ei, degi_out, degi_in);
  k_dscale<<<(NN+255)/256, 256, 0, stream>>>(degi_out, degi_in, dso, dsi);
  k_scan<<<1, 1024, 0, stream>>>(degi_in, rowptr, cursor, NN);
  k_fill<<<(NE+255)/256, 256, 0, stream>>>(ei, cursor, eidx);
  k_convw<<<768, 256, 0, stream>>>(Wl[0], Wl[1], Wl[2], Wt);
  k_prep0<<<(NN*64+255)/256, 256, 0, stream>>>(x, dso, hs);

  dim3 gg(391, 2);
  /* layer 0: residual = x (f32), bf16 out */
  k_agg<<<MPAD/4, 256, 0, stream>>>(hs, rowptr, eidx, agg);
  k_gemm<1,1><<<gg, 256, 0, stream>>>(agg, Wt, bl[0], dsi, x, nullptr, ob);
  k_stats<<<256, 256, 0, stream>>>(ob, ps, pq);
  k_statsfin2<<<1, 256, 0, stream>>>(ps, pq, gl[0], bel[0], cscale, cshift);
  k_norm<1><<<(NN*32+255)/256, 256, 0, stream>>>(ob, cscale, cshift, dso, h1, hs);
  /* layer 1: residual = h1 (bf16), bf16 out */
  k_agg<<<MPAD/4, 256, 0, stream>>>(hs, rowptr, eidx, agg);
  k_gemm<2,1><<<gg, 256, 0, stream>>>(agg, Wt + 65536, bl[1], dsi, nullptr, h1, ob);
  k_stats<<<256, 256, 0, stream>>>(ob, ps, pq);
  k_statsfin2<<<1, 256, 0, stream>>>(ps, pq, gl[1], bel[1], cscale, cshift);
  k_norm<0><<<(NN*32+255)/256, 256, 0, stream>>>(ob, cscale, cshift, dso, nullptr, hs);
  /* layer 2: no residual, no norm, f32 straight to d_out */
  k_agg<<<MPAD/4, 256, 0, stream>>>(hs, rowptr, eidx, agg);
  k_gemm<0,0><<<gg, 256, 0, stream>>>(agg, Wt + 2*65536, bl[2], dsi, nullptr, nullptr,
                                      d_out);
}

// Round 5
// 315.195 us; speedup vs baseline: 1.4328x; 1.4328x over previous
//
#include <hip/hip_runtime.h>
#include <hip/hip_bf16.h>
#include <stdint.h>

#define NN 50000
#define NE 400000
#define DD 256
#define MPAD 50048   /* 782*64 */
#define EPSV 1e-5f
#define NSB 49       /* scan blocks: 49*1024 >= NN */
#define NWID 1564    /* gemm stats writer rows: 782 blocks * 2 wm */

typedef __attribute__((ext_vector_type(8))) short bf16x8;
typedef __attribute__((ext_vector_type(8))) unsigned short u16x8;
typedef __attribute__((ext_vector_type(4))) float f32x4;

static __device__ __forceinline__ float bf2f(unsigned short u){
  union{unsigned int i; float f;} x; x.i=((unsigned int)u)<<16; return x.f;
}
static __device__ __forceinline__ unsigned short f2bf(float f){
  union{float f; unsigned int i;} x; x.f=f;
  return (unsigned short)((x.i + 0x7FFFu + ((x.i>>16)&1u))>>16);
}
static __device__ __forceinline__ void gl_lds16(const void* g, void* l){
  __builtin_amdgcn_global_load_lds((const __attribute__((address_space(1))) void*)g,
                                   (__attribute__((address_space(3))) void*)l, 16, 0, 0);
}

/* ---------------- graph preprocessing ---------------- */

__global__ void k_degree(const int* __restrict__ ei, int* __restrict__ degi_out,
                         int* __restrict__ degi_in){
  int e = blockIdx.x*256 + threadIdx.x;
  if(e < NE){
    atomicAdd(&degi_out[ei[e]], 1);
    atomicAdd(&degi_in[ei[NE + e]], 1);
  }
}

__global__ void k_dscale(const int* __restrict__ degi_out, const int* __restrict__ degi_in,
                         float* __restrict__ dso, float* __restrict__ dsi){
  int n = blockIdx.x*256 + threadIdx.x;
  if(n < NN){
    dso[n] = rsqrtf((float)max(degi_out[n],1));
    dsi[n] = rsqrtf((float)max(degi_in[n],1));
  }
}

/* parallel scan stage 1: per-block sums of degi_in */
__global__ void k_bsum(const int* __restrict__ cnt, int* __restrict__ bsum){
  __shared__ int wsum[16];
  int tid = threadIdx.x, lane = tid & 63, wv = tid >> 6;
  int i = blockIdx.x*1024 + tid;
  int v = (i < NN) ? cnt[i] : 0;
  for(int off=1; off<64; off<<=1) v += __shfl_xor(v, off);
  if(lane==0) wsum[wv] = v;
  __syncthreads();
  if(tid < 16){
    int t = wsum[tid];
    for(int off=1; off<16; off<<=1) t += __shfl_xor(t, off);
    if(tid==0) bsum[blockIdx.x] = t;
  }
}

/* stage 2: exclusive scan of NSB block sums (single wave) */
__global__ void k_bscan(const int* __restrict__ bsum, int* __restrict__ boff){
  int lane = threadIdx.x;
  int v = (lane < NSB) ? bsum[lane] : 0;
  int sc = v;
  for(int off=1; off<64; off<<=1){
    int t = __shfl_up(sc, off);
    if(lane >= off) sc += t;
  }
  if(lane < NSB) boff[lane] = sc - v;
}

/* stage 3: intra-block exclusive scan + block offset -> rowptr, cursor */
__global__ void k_scatter(const int* __restrict__ cnt, const int* __restrict__ boff,
                          int* __restrict__ rowptr, int* __restrict__ cursor){
  __shared__ int wsum[16];
  int tid = threadIdx.x, lane = tid & 63, wv = tid >> 6;
  int i = blockIdx.x*1024 + tid;
  int v = (i < NN) ? cnt[i] : 0;
  int sc = v;
  for(int off=1; off<64; off<<=1){
    int t = __shfl_up(sc, off);
    if(lane >= off) sc += t;
  }
  if(lane==63) wsum[wv] = sc;
  __syncthreads();
  if(wv==0){
    int t = (lane<16) ? wsum[lane] : 0;
    for(int off=1; off<16; off<<=1){
      int u = __shfl_up(t, off);
      if(lane >= off) t += u;
    }
    if(lane<16) wsum[lane] = t;
  }
  __syncthreads();
  int woff = (wv==0) ? 0 : wsum[wv-1];
  int ex = boff[blockIdx.x] + woff + sc - v;
  if(i < NN){ rowptr[i] = ex; cursor[i] = ex; }
  if(blockIdx.x==0 && tid==0) rowptr[NN] = NE;
}

__global__ void k_fill(const int* __restrict__ ei, int* __restrict__ cursor,
                       int* __restrict__ eidx){
  int e = blockIdx.x*256 + threadIdx.x;
  if(e < NE){
    int c = ei[NE + e];
    int p = atomicAdd(&cursor[c], 1);
    eidx[p] = ei[e];
  }
}

/* all 3 layers: W [K][Ncol] f32 -> Wt [Ncol][K] bf16 */
__global__ void k_convw(const float* __restrict__ W0, const float* __restrict__ W1,
                        const float* __restrict__ W2, unsigned short* __restrict__ Wt){
  int t = blockIdx.x*256 + threadIdx.x;   /* 3*65536 */
  int l = t >> 16, r = t & 65535;
  int k = r >> 8, n = r & 255;
  const float* W = (l==0) ? W0 : (l==1) ? W1 : W2;
  Wt[(size_t)l*65536 + n*256 + k] = f2bf(W[k*256 + n]);
}

/* hs = x * dso[row], bf16 */
__global__ void k_prep0(const float* __restrict__ x, const float* __restrict__ dso,
                        unsigned short* __restrict__ hs){
  int t = blockIdx.x*256 + threadIdx.x;   /* NN*64 */
  int row = t >> 6, c4 = (t & 63) << 2;
  if(row < NN){
    float s = dso[row];
    float4 v = *(const float4*)(x + (size_t)row*256 + c4);
    ushort4 o;
    o.x = f2bf(v.x*s); o.y = f2bf(v.y*s); o.z = f2bf(v.z*s); o.w = f2bf(v.w*s);
    *(ushort4*)(hs + (size_t)row*256 + c4) = o;
  }
}

/* one wave per destination node; index broadcast + 4 independent 16B gathers
   in flight per half-wave */
__global__ void k_agg(const unsigned short* __restrict__ hs, const int* __restrict__ rowptr,
                      const int* __restrict__ eidx, unsigned short* __restrict__ agg){
  int node = blockIdx.x*4 + (threadIdx.x >> 6);
  int lane = threadIdx.x & 63;
  int pair = lane >> 5, l32 = lane & 31;
  float a[8] = {0.f,0.f,0.f,0.f,0.f,0.f,0.f,0.f};
  int s = 0, e = 0;
  if(node < NN){ s = rowptr[node]; e = rowptr[node+1]; }
  int deg = e - s;
  for(int base=0; base<deg; base+=64){
    int cnt = min(deg - base, 64);
    int myidx = (base + lane < deg) ? eidx[s + base + lane] : 0;
    for(int g=0; g<cnt; g+=8){
      int jb = g + pair*4;
      int s0 = __shfl(myidx, jb+0);
      int s1 = __shfl(myidx, jb+1);
      int s2 = __shfl(myidx, jb+2);
      int s3 = __shfl(myidx, jb+3);
      u16x8 v0 = *(const u16x8*)(hs + (size_t)s0*256 + l32*8);
      u16x8 v1 = *(const u16x8*)(hs + (size_t)s1*256 + l32*8);
      u16x8 v2 = *(const u16x8*)(hs + (size_t)s2*256 + l32*8);
      u16x8 v3 = *(const u16x8*)(hs + (size_t)s3*256 + l32*8);
      if(jb+0 < cnt){
        #pragma unroll
        for(int k2=0;k2<8;k2++) a[k2] += bf2f(v0[k2]);
      }
      if(jb+1 < cnt){
        #pragma unroll
        for(int k2=0;k2<8;k2++) a[k2] += bf2f(v1[k2]);
      }
      if(jb+2 < cnt){
        #pragma unroll
        for(int k2=0;k2<8;k2++) a[k2] += bf2f(v2[k2]);
      }
      if(jb+3 < cnt){
        #pragma unroll
        for(int k2=0;k2<8;k2++) a[k2] += bf2f(v3[k2]);
      }
    }
  }
  #pragma unroll
  for(int k2=0;k2<8;k2++) a[k2] += __shfl_xor(a[k2], 32);
  if(pair==0 && node < MPAD){
    u16x8 o;
    #pragma unroll
    for(int k2=0;k2<8;k2++) o[k2] = f2bf(a[k2]);
    *(u16x8*)(agg + (size_t)node*256 + l32*8) = o;
  }
}

/* GEMM 64x128 tile, BK=64, single 24KB LDS buffer, barrier loop.
   out[m][n] = (sum_k A[m][k]*W[k][n] + b[n]) * dsi[m] (+ residual).
   STATS: write per-(block,wm) column partial sums to ps/pq (no atomics).
   RESMODE: 0=none, 1=f32 residual, 2=bf16 residual. OUTBF: bf16 vs f32 out. */
template<int RESMODE, int STATS, int OUTBF>
__global__ __launch_bounds__(256) void k_gemm(
    const unsigned short* __restrict__ A,    /* [MPAD][256] bf16 */
    const unsigned short* __restrict__ Bt,   /* [256][256] bf16 = W^T */
    const float* __restrict__ bias,
    const float* __restrict__ dsi,
    const float* __restrict__ resf,
    const unsigned short* __restrict__ resb,
    void* __restrict__ outp,
    float* __restrict__ ps, float* __restrict__ pq)
{
  __shared__ __align__(16) unsigned char smem[24576];   /* A 8KB + B 16KB */
  unsigned char* smA = smem;
  unsigned char* smB = smem + 8192;
  const int tid = threadIdx.x;
  const int w = tid >> 6, lane = tid & 63;
  const int m0 = blockIdx.x * 64, n0 = blockIdx.y * 128;
  const int wm = w & 1, wn = w >> 1;

  f32x4 acc[2][4];
  #pragma unroll
  for(int i=0;i<2;i++)
    #pragma unroll
    for(int j=0;j<4;j++) acc[i][j] = (f32x4){0.f,0.f,0.f,0.f};

  const char* Ab = (const char*)A;
  const char* Bb = (const char*)Bt;

  for(int kt=0; kt<4; ++kt){
    /* stage A: 512 chunks of 16B (64 rows x 8), 2 per thread */
    #pragma unroll
    for(int it=0; it<2; ++it){
      const int flat = it*256 + tid;
      const int row = flat >> 3, ch = flat & 7;
      const int sw = ch ^ (row & 7);
      gl_lds16(Ab + (size_t)(m0+row)*512 + kt*128 + sw*16,
               smA + (size_t)(it*256 + w*64)*16);
    }
    /* stage B: 1024 chunks (128 rows x 8), 4 per thread */
    #pragma unroll
    for(int it=0; it<4; ++it){
      const int flat = it*256 + tid;
      const int row = flat >> 3, ch = flat & 7;
      const int sw = ch ^ (row & 7);
      gl_lds16(Bb + (size_t)(n0+row)*512 + kt*128 + sw*16,
               smB + (size_t)(it*256 + w*64)*16);
    }
    __syncthreads();
    #pragma unroll
    for(int ks=0; ks<2; ++ks){
      const int ca = ks*4 + (lane >> 4);
      bf16x8 av[2], bv[4];
      #pragma unroll
      for(int f=0; f<2; ++f){
        const int ra = wm*32 + f*16 + (lane & 15);
        av[f] = *(const bf16x8*)(smA + ra*128 + ((ca ^ (ra & 7)) << 4));
      }
      #pragma unroll
      for(int f=0; f<4; ++f){
        const int rb = wn*64 + f*16 + (lane & 15);
        bv[f] = *(const bf16x8*)(smB + rb*128 + ((ca ^ (rb & 7)) << 4));
      }
      #pragma unroll
      for(int mf=0; mf<2; ++mf)
        #pragma unroll
        for(int nf=0; nf<4; ++nf)
          acc[mf][nf] = __builtin_amdgcn_mfma_f32_16x16x32_bf16(av[mf], bv[nf], acc[mf][nf], 0,0,0);
    }
    __syncthreads();
  }

  /* epilogue: C row = (lane>>4)*4+j, col = lane&15 (per 16x16 frag) */
  const int colb = n0 + wn*64 + (lane & 15);
  float bs[4];
  #pragma unroll
  for(int nf=0; nf<4; ++nf) bs[nf] = bias[colb + nf*16];
  float s[4] = {0.f,0.f,0.f,0.f}, q[4] = {0.f,0.f,0.f,0.f};
  #pragma unroll
  for(int mf=0; mf<2; ++mf){
    const int growb = m0 + wm*32 + mf*16 + ((lane>>4)<<2);
    float rv[16];
    if(RESMODE){
      #pragma unroll
      for(int j=0; j<4; ++j){
        const int grow = growb + j;
        if(grow < NN){
          const size_t rb = (size_t)grow * 256;
          #pragma unroll
          for(int nf=0; nf<4; ++nf)
            rv[j*4+nf] = (RESMODE==1) ? resf[rb + colb + nf*16]
                                      : bf2f(resb[rb + colb + nf*16]);
        }
      }
    }
    #pragma unroll
    for(int j=0; j<4; ++j){
      const int grow = growb + j;
      if(grow < NN){
        const float d = dsi[grow];
        const size_t rb = (size_t)grow * 256;
        #pragma unroll
        for(int nf=0; nf<4; ++nf){
          float v = (acc[mf][nf][j] + bs[nf]) * d;
          if(RESMODE) v += rv[j*4+nf];
          if(OUTBF) ((unsigned short*)outp)[rb + colb + nf*16] = f2bf(v);
          else      ((float*)outp)[rb + colb + nf*16] = v;
          if(STATS){ s[nf] += v; q[nf] += v*v; }
        }
      }
    }
  }
  if(STATS){
    const int wid = blockIdx.x*2 + wm;
    #pragma unroll
    for(int nf=0; nf<4; ++nf){
      float sv = s[nf], qv = q[nf];
      sv += __shfl_xor(sv, 16); sv += __shfl_xor(sv, 32);
      qv += __shfl_xor(qv, 16); qv += __shfl_xor(qv, 32);
      if(lane < 16){
        ps[(size_t)wid*256 + colb + nf*16] = sv;
        pq[(size_t)wid*256 + colb + nf*16] = qv;
      }
    }
  }
}

/* reduce NWID partial rows -> 32 rows (coalesced) */
__global__ void k_statsred(const float* __restrict__ ps, const float* __restrict__ pq,
                           float* __restrict__ prs, float* __restrict__ prq){
  int c = threadIdx.x, b = blockIdx.x;
  float s = 0.f, q = 0.f;
  for(int i = b; i < NWID; i += 32){
    s += ps[(size_t)i*256 + c];
    q += pq[(size_t)i*256 + c];
  }
  prs[b*256 + c] = s;
  prq[b*256 + c] = q;
}

__global__ void k_statsfin(const float* __restrict__ prs, const float* __restrict__ prq,
                           const float* __restrict__ g, const float* __restrict__ be,
                           float* __restrict__ cscale, float* __restrict__ cshift){
  int c = threadIdx.x;
  float s = 0.f, q = 0.f;
  for(int b = 0; b < 32; ++b){ s += prs[b*256 + c]; q += prq[b*256 + c]; }
  float mu  = s * (1.0f/NN);
  float var = q * (1.0f/NN) - mu*mu;
  var = fmaxf(var, 0.f);
  float inv = rsqrtf(var + EPSV);
  float sc = g[c] * inv;
  cscale[c] = sc;
  cshift[c] = be[c] - mu * sc;
}

/* y = relu(ob*cscale+cshift); optionally keep bf16 h (residual for next layer);
   always emit bf16 y*dso (next gather source) */
template<int WRITE_H>
__global__ void k_norm(const unsigned short* __restrict__ ob, const float* __restrict__ cscale,
                       const float* __restrict__ cshift, const float* __restrict__ dso,
                       unsigned short* __restrict__ h1, unsigned short* __restrict__ hs){
  int t = blockIdx.x*256 + threadIdx.x;   /* NN*32 */
  int row = t >> 5, c8 = (t & 31) << 3;
  if(row >= NN) return;
  u16x8 v = *(const u16x8*)(ob + (size_t)row*256 + c8);
  float s = dso[row];
  u16x8 oh, os;
  #pragma unroll
  for(int k2=0;k2<8;k2++){
    float y = fmaxf(bf2f(v[k2])*cscale[c8+k2] + cshift[c8+k2], 0.f);
    oh[k2] = f2bf(y);
    os[k2] = f2bf(y*s);
  }
  if(WRITE_H) *(u16x8*)(h1 + (size_t)row*256 + c8) = oh;
  *(u16x8*)(hs + (size_t)row*256 + c8) = os;
}

extern "C" void kernel_launch(void* const* d_in, const int* in_sizes, int n_in,
                              void* d_out, int out_size, void* d_ws, size_t ws_size,
                              hipStream_t stream){
  (void)in_sizes; (void)n_in; (void)out_size;
  const float* x  = (const float*)d_in[0];
  const int*   ei = (const int*)d_in[1];
  const float* Wl[3]  = {(const float*)d_in[2], (const float*)d_in[6], (const float*)d_in[10]};
  const float* bl[3]  = {(const float*)d_in[3], (const float*)d_in[7], (const float*)d_in[11]};
  const float* gl[2]  = {(const float*)d_in[4], (const float*)d_in[8]};
  const float* bel[2] = {(const float*)d_in[5], (const float*)d_in[9]};

  char* base = (char*)d_ws;
  size_t off = 0;
  auto alloc = [&](size_t bytes)->char* {
    char* r = base + off;
    off = (off + bytes + 511) & ~(size_t)511;
    return r;
  };
  int* degi_out = (int*)alloc((size_t)2*NN*4);
  int* degi_in  = degi_out + NN;
  float* dso    = (float*)alloc((size_t)NN*4);
  float* dsi    = (float*)alloc((size_t)NN*4);
  int* rowptr   = (int*)alloc((size_t)(NN+1)*4);
  int* cursor   = (int*)alloc((size_t)NN*4);
  int* eidx     = (int*)alloc((size_t)NE*4);
  int* bsum     = (int*)alloc((size_t)NSB*4);
  int* boff     = (int*)alloc((size_t)NSB*4);
  unsigned short* Wt = (unsigned short*)alloc((size_t)3*65536*2);
  float* ps     = (float*)alloc((size_t)NWID*256*4);
  float* pq     = (float*)alloc((size_t)NWID*256*4);
  float* prs    = (float*)alloc((size_t)32*256*4);
  float* prq    = (float*)alloc((size_t)32*256*4);
  float* cscale = (float*)alloc(1024);
  float* cshift = (float*)alloc(1024);
  unsigned short* hs  = (unsigned short*)alloc((size_t)MPAD*256*2);
  unsigned short* agg = (unsigned short*)alloc((size_t)MPAD*256*2);
  unsigned short* h1  = (unsigned short*)alloc((size_t)MPAD*256*2);
  unsigned short* ob  = (unsigned short*)alloc((size_t)MPAD*256*2);
  if(off > ws_size) return;   /* workspace too small: fail visibly */

  /* graph prep (layer-invariant) */
  hipMemsetAsync(degi_out, 0, (size_t)2*NN*4, stream);
  k_degree<<<(NE+255)/256, 256, 0, stream>>>(ei, degi_out, degi_in);
  k_dscale<<<(NN+255)/256, 256, 0, stream>>>(degi_out, degi_in, dso, dsi);
  k_bsum<<<NSB, 1024, 0, stream>>>(degi_in, bsum);
  k_bscan<<<1, 64, 0, stream>>>(bsum, boff);
  k_scatter<<<NSB, 1024, 0, stream>>>(degi_in, boff, rowptr, cursor);
  k_fill<<<(NE+255)/256, 256, 0, stream>>>(ei, cursor, eidx);
  k_convw<<<768, 256, 0, stream>>>(Wl[0], Wl[1], Wl[2], Wt);
  k_prep0<<<(NN*64+255)/256, 256, 0, stream>>>(x, dso, hs);

  dim3 gg(782, 2);
  /* layer 0: residual = x (f32), stats, bf16 out */
  k_agg<<<MPAD/4, 256, 0, stream>>>(hs, rowptr, eidx, agg);
  k_gemm<1,1,1><<<gg, 256, 0, stream>>>(agg, Wt, bl[0], dsi, x, nullptr, ob, ps, pq);
  k_statsred<<<32, 256, 0, stream>>>(ps, pq, prs, prq);
  k_statsfin<<<1, 256, 0, stream>>>(prs, prq, gl[0], bel[0], cscale, cshift);
  k_norm<1><<<(NN*32+255)/256, 256, 0, stream>>>(ob, cscale, cshift, dso, h1, hs);
  /* layer 1: residual = h1 (bf16), stats, bf16 out */
  k_agg<<<MPAD/4, 256, 0, stream>>>(hs, rowptr, eidx, agg);
  k_gemm<2,1,1><<<gg, 256, 0, stream>>>(agg, Wt + 65536, bl[1], dsi, nullptr, h1, ob, ps, pq);
  k_statsred<<<32, 256, 0, stream>>>(ps, pq, prs, prq);
  k_statsfin<<<1, 256, 0, stream>>>(prs, prq, gl[1], bel[1], cscale, cshift);
  k_norm<0><<<(NN*32+255)/256, 256, 0, stream>>>(ob, cscale, cshift, dso, nullptr, hs);
  /* layer 2: no residual, no norm, f32 straight to d_out */
  k_agg<<<MPAD/4, 256, 0, stream>>>(hs, rowptr, eidx, agg);
  k_gemm<0,0,0><<<gg, 256, 0, stream>>>(agg, Wt + 2*65536, bl[2], dsi, nullptr, nullptr,
                                        d_out, nullptr, nullptr);
}

// Round 6
// 282.827 us; speedup vs baseline: 1.5968x; 1.1144x over previous
//
#include <hip/hip_runtime.h>
#include <hip/hip_bf16.h>
#include <stdint.h>

#define NN 50000
#define NE 400000
#define DD 256
#define MPAD 50048   /* 782*64 */
#define EPSV 1e-5f
#define NSB 49       /* scan blocks: 49*1024 >= NN */
#define NWID 1564    /* gemm stats writer rows: 782 m-blocks * 2 wm */

typedef __attribute__((ext_vector_type(8))) short bf16x8;
typedef __attribute__((ext_vector_type(8))) unsigned short u16x8;
typedef __attribute__((ext_vector_type(4))) float f32x4;

static __device__ __forceinline__ float bf2f(unsigned short u){
  union{unsigned int i; float f;} x; x.i=((unsigned int)u)<<16; return x.f;
}
static __device__ __forceinline__ unsigned short f2bf(float f){
  union{float f; unsigned int i;} x; x.f=f;
  return (unsigned short)((x.i + 0x7FFFu + ((x.i>>16)&1u))>>16);
}
static __device__ __forceinline__ void gl_lds16(const void* g, void* l){
  __builtin_amdgcn_global_load_lds((const __attribute__((address_space(1))) void*)g,
                                   (__attribute__((address_space(3))) void*)l, 16, 0, 0);
}

/* ---------------- graph preprocessing ---------------- */

__global__ void k_degree(const int* __restrict__ ei, int* __restrict__ degi_out,
                         int* __restrict__ degi_in){
  int e = blockIdx.x*256 + threadIdx.x;
  if(e < NE){
    atomicAdd(&degi_out[ei[e]], 1);
    atomicAdd(&degi_in[ei[NE + e]], 1);
  }
}

__global__ void k_dscale(const int* __restrict__ degi_out, const int* __restrict__ degi_in,
                         float* __restrict__ dso, float* __restrict__ dsi){
  int n = blockIdx.x*256 + threadIdx.x;
  if(n < NN){
    dso[n] = rsqrtf((float)max(degi_out[n],1));
    dsi[n] = rsqrtf((float)max(degi_in[n],1));
  }
}

/* parallel scan stage 1: per-block sums of degi_in */
__global__ void k_bsum(const int* __restrict__ cnt, int* __restrict__ bsum){
  __shared__ int wsum[16];
  int tid = threadIdx.x, lane = tid & 63, wv = tid >> 6;
  int i = blockIdx.x*1024 + tid;
  int v = (i < NN) ? cnt[i] : 0;
  for(int off=1; off<64; off<<=1) v += __shfl_xor(v, off);
  if(lane==0) wsum[wv] = v;
  __syncthreads();
  if(tid < 16){
    int t = wsum[tid];
    for(int off=1; off<16; off<<=1) t += __shfl_xor(t, off);
    if(tid==0) bsum[blockIdx.x] = t;
  }
}

/* stage 2: exclusive scan of NSB block sums (single wave) */
__global__ void k_bscan(const int* __restrict__ bsum, int* __restrict__ boff){
  int lane = threadIdx.x;
  int v = (lane < NSB) ? bsum[lane] : 0;
  int sc = v;
  for(int off=1; off<64; off<<=1){
    int t = __shfl_up(sc, off);
    if(lane >= off) sc += t;
  }
  if(lane < NSB) boff[lane] = sc - v;
}

/* stage 3: intra-block exclusive scan + block offset -> rowptr, cursor */
__global__ void k_scatter(const int* __restrict__ cnt, const int* __restrict__ boff,
                          int* __restrict__ rowptr, int* __restrict__ cursor){
  __shared__ int wsum[16];
  int tid = threadIdx.x, lane = tid & 63, wv = tid >> 6;
  int i = blockIdx.x*1024 + tid;
  int v = (i < NN) ? cnt[i] : 0;
  int sc = v;
  for(int off=1; off<64; off<<=1){
    int t = __shfl_up(sc, off);
    if(lane >= off) sc += t;
  }
  if(lane==63) wsum[wv] = sc;
  __syncthreads();
  if(wv==0){
    int t = (lane<16) ? wsum[lane] : 0;
    for(int off=1; off<16; off<<=1){
      int u = __shfl_up(t, off);
      if(lane >= off) t += u;
    }
    if(lane<16) wsum[lane] = t;
  }
  __syncthreads();
  int woff = (wv==0) ? 0 : wsum[wv-1];
  int ex = boff[blockIdx.x] + woff + sc - v;
  if(i < NN){ rowptr[i] = ex; cursor[i] = ex; }
  if(blockIdx.x==0 && tid==0) rowptr[NN] = NE;
}

__global__ void k_fill(const int* __restrict__ ei, int* __restrict__ cursor,
                       int* __restrict__ eidx){
  int e = blockIdx.x*256 + threadIdx.x;
  if(e < NE){
    int c = ei[NE + e];
    int p = atomicAdd(&cursor[c], 1);
    eidx[p] = ei[e];
  }
}

/* all 3 layers: W [K][Ncol] f32 -> Wt [Ncol][K] bf16 */
__global__ void k_convw(const float* __restrict__ W0, const float* __restrict__ W1,
                        const float* __restrict__ W2, unsigned short* __restrict__ Wt){
  int t = blockIdx.x*256 + threadIdx.x;   /* 3*65536 */
  int l = t >> 16, r = t & 65535;
  int k = r >> 8, n = r & 255;
  const float* W = (l==0) ? W0 : (l==1) ? W1 : W2;
  Wt[(size_t)l*65536 + n*256 + k] = f2bf(W[k*256 + n]);
}

/* hs = x * dso[row], bf16 (layer-0 gather source) */
__global__ void k_prep0(const float* __restrict__ x, const float* __restrict__ dso,
                        unsigned short* __restrict__ hs){
  int t = blockIdx.x*256 + threadIdx.x;   /* NN*64 */
  int row = t >> 6, c4 = (t & 63) << 2;
  if(row < NN){
    float s = dso[row];
    float4 v = *(const float4*)(x + (size_t)row*256 + c4);
    ushort4 o;
    o.x = f2bf(v.x*s); o.y = f2bf(v.y*s); o.z = f2bf(v.z*s); o.w = f2bf(v.w*s);
    *(ushort4*)(hs + (size_t)row*256 + c4) = o;
  }
}

/* one wave per destination node; index broadcast + 8 independent 16B gathers
   in flight per half-wave (16 edges per wave iteration).
   NORM=1: gather source = raw prev layer out (bf16); apply
   relu(fma(v,cs,ch)) * dso[src] on the fly (fused BatchNorm+ReLU+scale). */
template<int NORM>
__global__ void k_agg(const unsigned short* __restrict__ src, const int* __restrict__ rowptr,
                      const int* __restrict__ eidx,
                      const float* __restrict__ cs, const float* __restrict__ ch,
                      const float* __restrict__ dso,
                      unsigned short* __restrict__ agg){
  int node = blockIdx.x*4 + (threadIdx.x >> 6);
  int lane = threadIdx.x & 63;
  int pair = lane >> 5, l32 = lane & 31;
  float csr[8], chr[8];
  if(NORM){
    #pragma unroll
    for(int k2=0;k2<8;k2++){ csr[k2] = cs[l32*8+k2]; chr[k2] = ch[l32*8+k2]; }
  }
  float a[8] = {0.f,0.f,0.f,0.f,0.f,0.f,0.f,0.f};
  int s = 0, e = 0;
  if(node < NN){ s = rowptr[node]; e = rowptr[node+1]; }
  int deg = e - s;
  for(int base=0; base<deg; base+=64){
    int cnt = min(deg - base, 64);
    int myidx = (base + lane < deg) ? eidx[s + base + lane] : 0;
    for(int g=0; g<cnt; g+=16){
      int jb = g + pair*8;
      int si[8];
      #pragma unroll
      for(int i=0;i<8;i++) si[i] = __shfl(myidx, jb+i);
      /* 8 unconditional 16B gathers in flight (OOR lanes hit row 0 - safe) */
      u16x8 v[8];
      #pragma unroll
      for(int i=0;i<8;i++) v[i] = *(const u16x8*)(src + (size_t)si[i]*256 + l32*8);
      float d[8];
      if(NORM){
        #pragma unroll
        for(int i=0;i<8;i++) d[i] = dso[si[i]];
      }
      #pragma unroll
      for(int i=0;i<8;i++){
        if(jb+i < cnt){
          #pragma unroll
          for(int k2=0;k2<8;k2++){
            float y = bf2f(v[i][k2]);
            if(NORM) y = fmaxf(fmaf(y, csr[k2], chr[k2]), 0.f) * d[i];
            a[k2] += y;
          }
        }
      }
    }
  }
  #pragma unroll
  for(int k2=0;k2<8;k2++) a[k2] += __shfl_xor(a[k2], 32);
  if(pair==0 && node < MPAD){
    u16x8 o;
    #pragma unroll
    for(int k2=0;k2<8;k2++) o[k2] = f2bf(a[k2]);
    *(u16x8*)(agg + (size_t)node*256 + l32*8) = o;
  }
}

/* GEMM 64x128 tile, BK=64, single 24KB LDS buffer.
   grid (2, 782): x = n-half (fast), y = m-block -> consecutive dispatches
   share the A-tile (L2 locality).
   out[m][n] = (sum_k A[m][k]*W[k][n] + b[n]) * dsi[m] (+ residual).
   RESMODE: 0=none, 1=f32 residual, 3=bf16 prev-out + fused norm+relu residual.
   STATS: per-(m-block,wm) column partials, no atomics. OUTBF: bf16 vs f32. */
template<int RESMODE, int STATS, int OUTBF>
__global__ __launch_bounds__(256) void k_gemm(
    const unsigned short* __restrict__ A,    /* [MPAD][256] bf16 */
    const unsigned short* __restrict__ Bt,   /* [256][256] bf16 = W^T */
    const float* __restrict__ bias,
    const float* __restrict__ dsi,
    const float* __restrict__ resf,
    const unsigned short* __restrict__ resb,
    const float* __restrict__ rcs, const float* __restrict__ rch,
    void* __restrict__ outp,
    float* __restrict__ ps, float* __restrict__ pq)
{
  __shared__ __align__(16) unsigned char smem[24576];   /* A 8KB + B 16KB */
  unsigned char* smA = smem;
  unsigned char* smB = smem + 8192;
  const int tid = threadIdx.x;
  const int w = tid >> 6, lane = tid & 63;
  const int m0 = blockIdx.y * 64, n0 = blockIdx.x * 128;
  const int wm = w & 1, wn = w >> 1;

  f32x4 acc[2][4];
  #pragma unroll
  for(int i=0;i<2;i++)
    #pragma unroll
    for(int j=0;j<4;j++) acc[i][j] = (f32x4){0.f,0.f,0.f,0.f};

  const char* Ab = (const char*)A;
  const char* Bb = (const char*)Bt;

  for(int kt=0; kt<4; ++kt){
    #pragma unroll
    for(int it=0; it<2; ++it){
      const int flat = it*256 + tid;
      const int row = flat >> 3, ch_ = flat & 7;
      const int sw = ch_ ^ (row & 7);
      gl_lds16(Ab + (size_t)(m0+row)*512 + kt*128 + sw*16,
               smA + (size_t)(it*256 + w*64)*16);
    }
    #pragma unroll
    for(int it=0; it<4; ++it){
      const int flat = it*256 + tid;
      const int row = flat >> 3, ch_ = flat & 7;
      const int sw = ch_ ^ (row & 7);
      gl_lds16(Bb + (size_t)(n0+row)*512 + kt*128 + sw*16,
               smB + (size_t)(it*256 + w*64)*16);
    }
    __syncthreads();
    #pragma unroll
    for(int ks=0; ks<2; ++ks){
      const int ca = ks*4 + (lane >> 4);
      bf16x8 av[2], bv[4];
      #pragma unroll
      for(int f=0; f<2; ++f){
        const int ra = wm*32 + f*16 + (lane & 15);
        av[f] = *(const bf16x8*)(smA + ra*128 + ((ca ^ (ra & 7)) << 4));
      }
      #pragma unroll
      for(int f=0; f<4; ++f){
        const int rb = wn*64 + f*16 + (lane & 15);
        bv[f] = *(const bf16x8*)(smB + rb*128 + ((ca ^ (rb & 7)) << 4));
      }
      #pragma unroll
      for(int mf=0; mf<2; ++mf)
        #pragma unroll
        for(int nf=0; nf<4; ++nf)
          acc[mf][nf] = __builtin_amdgcn_mfma_f32_16x16x32_bf16(av[mf], bv[nf], acc[mf][nf], 0,0,0);
    }
    __syncthreads();
  }

  /* epilogue: C row = (lane>>4)*4+j, col = lane&15 (per 16x16 frag) */
  const int colb = n0 + wn*64 + (lane & 15);
  float bs[4], rcsv[4], rchv[4];
  #pragma unroll
  for(int nf=0; nf<4; ++nf) bs[nf] = bias[colb + nf*16];
  if(RESMODE==3){
    #pragma unroll
    for(int nf=0; nf<4; ++nf){ rcsv[nf] = rcs[colb + nf*16]; rchv[nf] = rch[colb + nf*16]; }
  }
  float s[4] = {0.f,0.f,0.f,0.f}, q[4] = {0.f,0.f,0.f,0.f};
  #pragma unroll
  for(int mf=0; mf<2; ++mf){
    const int growb = m0 + wm*32 + mf*16 + ((lane>>4)<<2);
    float rv[16];
    if(RESMODE){
      #pragma unroll
      for(int j=0; j<4; ++j){
        const int grow = growb + j;
        if(grow < NN){
          const size_t rb = (size_t)grow * 256;
          #pragma unroll
          for(int nf=0; nf<4; ++nf){
            if(RESMODE==1) rv[j*4+nf] = resf[rb + colb + nf*16];
            else rv[j*4+nf] = fmaxf(fmaf(bf2f(resb[rb + colb + nf*16]), rcsv[nf], rchv[nf]), 0.f);
          }
        }
      }
    }
    #pragma unroll
    for(int j=0; j<4; ++j){
      const int grow = growb + j;
      if(grow < NN){
        const float d = dsi[grow];
        const size_t rb = (size_t)grow * 256;
        #pragma unroll
        for(int nf=0; nf<4; ++nf){
          float v = (acc[mf][nf][j] + bs[nf]) * d;
          if(RESMODE) v += rv[j*4+nf];
          if(OUTBF) ((unsigned short*)outp)[rb + colb + nf*16] = f2bf(v);
          else      ((float*)outp)[rb + colb + nf*16] = v;
          if(STATS){ s[nf] += v; q[nf] += v*v; }
        }
      }
    }
  }
  if(STATS){
    const int wid = blockIdx.y*2 + wm;
    #pragma unroll
    for(int nf=0; nf<4; ++nf){
      float sv = s[nf], qv = q[nf];
      sv += __shfl_xor(sv, 16); sv += __shfl_xor(sv, 32);
      qv += __shfl_xor(qv, 16); qv += __shfl_xor(qv, 32);
      if(lane < 16){
        ps[(size_t)wid*256 + colb + nf*16] = sv;
        pq[(size_t)wid*256 + colb + nf*16] = qv;
      }
    }
  }
}

/* one block per column: reduce NWID partials, finalize cscale/cshift */
__global__ void k_statsall(const float* __restrict__ ps, const float* __restrict__ pq,
                           const float* __restrict__ g, const float* __restrict__ be,
                           float* __restrict__ cs, float* __restrict__ ch){
  __shared__ float rs[4], rq[4];
  int c = blockIdx.x, t = threadIdx.x;
  float s = 0.f, q = 0.f;
  for(int r = t; r < NWID; r += 256){
    s += ps[(size_t)r*256 + c];
    q += pq[(size_t)r*256 + c];
  }
  for(int off=1; off<64; off<<=1){ s += __shfl_xor(s, off); q += __shfl_xor(q, off); }
  if((t & 63) == 0){ rs[t>>6] = s; rq[t>>6] = q; }
  __syncthreads();
  if(t == 0){
    float S = rs[0]+rs[1]+rs[2]+rs[3], Q = rq[0]+rq[1]+rq[2]+rq[3];
    float mu  = S * (1.0f/NN);
    float var = fmaxf(Q * (1.0f/NN) - mu*mu, 0.f);
    float inv = rsqrtf(var + EPSV);
    float sc = g[c] * inv;
    cs[c] = sc;
    ch[c] = be[c] - mu * sc;
  }
}

extern "C" void kernel_launch(void* const* d_in, const int* in_sizes, int n_in,
                              void* d_out, int out_size, void* d_ws, size_t ws_size,
                              hipStream_t stream){
  (void)in_sizes; (void)n_in; (void)out_size;
  const float* x  = (const float*)d_in[0];
  const int*   ei = (const int*)d_in[1];
  const float* Wl[3]  = {(const float*)d_in[2], (const float*)d_in[6], (const float*)d_in[10]};
  const float* bl[3]  = {(const float*)d_in[3], (const float*)d_in[7], (const float*)d_in[11]};
  const float* gl[2]  = {(const float*)d_in[4], (const float*)d_in[8]};
  const float* bel[2] = {(const float*)d_in[5], (const float*)d_in[9]};

  char* base = (char*)d_ws;
  size_t off = 0;
  auto alloc = [&](size_t bytes)->char* {
    char* r = base + off;
    off = (off + bytes + 511) & ~(size_t)511;
    return r;
  };
  int* degi_out = (int*)alloc((size_t)2*NN*4);
  int* degi_in  = degi_out + NN;
  float* dso    = (float*)alloc((size_t)NN*4);
  float* dsi    = (float*)alloc((size_t)NN*4);
  int* rowptr   = (int*)alloc((size_t)(NN+1)*4);
  int* cursor   = (int*)alloc((size_t)NN*4);
  int* eidx     = (int*)alloc((size_t)NE*4);
  int* bsum     = (int*)alloc((size_t)NSB*4);
  int* boff     = (int*)alloc((size_t)NSB*4);
  unsigned short* Wt = (unsigned short*)alloc((size_t)3*65536*2);
  float* ps     = (float*)alloc((size_t)NWID*256*4);
  float* pq     = (float*)alloc((size_t)NWID*256*4);
  float* cs0    = (float*)alloc(1024);
  float* ch0    = (float*)alloc(1024);
  float* cs1    = (float*)alloc(1024);
  float* ch1    = (float*)alloc(1024);
  unsigned short* hs  = (unsigned short*)alloc((size_t)MPAD*256*2);
  unsigned short* agg = (unsigned short*)alloc((size_t)MPAD*256*2);
  unsigned short* ob0 = (unsigned short*)alloc((size_t)MPAD*256*2);
  unsigned short* ob1 = (unsigned short*)alloc((size_t)MPAD*256*2);
  if(off > ws_size) return;   /* workspace too small: fail visibly */

  /* graph prep (layer-invariant) */
  (void)hipMemsetAsync(degi_out, 0, (size_t)2*NN*4, stream);
  k_degree<<<(NE+255)/256, 256, 0, stream>>>(ei, degi_out, degi_in);
  k_dscale<<<(NN+255)/256, 256, 0, stream>>>(degi_out, degi_in, dso, dsi);
  k_bsum<<<NSB, 1024, 0, stream>>>(degi_in, bsum);
  k_bscan<<<1, 64, 0, stream>>>(bsum, boff);
  k_scatter<<<NSB, 1024, 0, stream>>>(degi_in, boff, rowptr, cursor);
  k_fill<<<(NE+255)/256, 256, 0, stream>>>(ei, cursor, eidx);
  k_convw<<<768, 256, 0, stream>>>(Wl[0], Wl[1], Wl[2], Wt);
  k_prep0<<<(NN*64+255)/256, 256, 0, stream>>>(x, dso, hs);

  dim3 gg(2, 782);
  /* layer 0: gather hs0, residual = x (f32), stats -> ob0 */
  k_agg<0><<<MPAD/4, 256, 0, stream>>>(hs, rowptr, eidx, nullptr, nullptr, nullptr, agg);
  k_gemm<1,1,1><<<gg, 256, 0, stream>>>(agg, Wt, bl[0], dsi, x, nullptr, nullptr, nullptr,
                                        ob0, ps, pq);
  k_statsall<<<256, 256, 0, stream>>>(ps, pq, gl[0], bel[0], cs0, ch0);
  /* layer 1: gather = norm0(ob0) on the fly; residual = norm0(ob0) in epilogue */
  k_agg<1><<<MPAD/4, 256, 0, stream>>>(ob0, rowptr, eidx, cs0, ch0, dso, agg);
  k_gemm<3,1,1><<<gg, 256, 0, stream>>>(agg, Wt + 65536, bl[1], dsi, nullptr, ob0, cs0, ch0,
                                        ob1, ps, pq);
  k_statsall<<<256, 256, 0, stream>>>(ps, pq, gl[1], bel[1], cs1, ch1);
  /* layer 2: gather = norm1(ob1) on the fly; no residual, f32 out */
  k_agg<1><<<MPAD/4, 256, 0, stream>>>(ob1, rowptr, eidx, cs1, ch1, dso, agg);
  k_gemm<0,0,0><<<gg, 256, 0, stream>>>(agg, Wt + 2*65536, bl[2], dsi, nullptr, nullptr,
                                        nullptr, nullptr, d_out, nullptr, nullptr);
}

// Round 7
// 274.140 us; speedup vs baseline: 1.6474x; 1.0317x over previous
//
#include <hip/hip_runtime.h>
#include <hip/hip_bf16.h>
#include <stdint.h>

#define NN 50000
#define NE 400000
#define DD 256
#define MPAD 50048   /* 782*64 */
#define EPSV 1e-5f
#define NSB 49       /* scan blocks: 49*1024 >= NN */
#define NWID 1564    /* gemm stats writer rows: 782 m-blocks * 2 wm */

typedef __attribute__((ext_vector_type(8))) short bf16x8;
typedef __attribute__((ext_vector_type(8))) unsigned short u16x8;
typedef __attribute__((ext_vector_type(4))) float f32x4;

static __device__ __forceinline__ float bf2f(unsigned short u){
  union{unsigned int i; float f;} x; x.i=((unsigned int)u)<<16; return x.f;
}
static __device__ __forceinline__ unsigned short f2bf(float f){
  union{float f; unsigned int i;} x; x.f=f;
  return (unsigned short)((x.i + 0x7FFFu + ((x.i>>16)&1u))>>16);
}
static __device__ __forceinline__ void gl_lds16(const void* g, void* l){
  __builtin_amdgcn_global_load_lds((const __attribute__((address_space(1))) void*)g,
                                   (__attribute__((address_space(3))) void*)l, 16, 0, 0);
}

/* ---------------- graph preprocessing ---------------- */

__global__ void k_degree(const int* __restrict__ ei, int* __restrict__ degi_out,
                         int* __restrict__ degi_in){
  int e = blockIdx.x*256 + threadIdx.x;
  if(e < NE){
    atomicAdd(&degi_out[ei[e]], 1);
    atomicAdd(&degi_in[ei[NE + e]], 1);
  }
}

/* per-block sums of degi_in (+ fused dso/dsi compute) */
__global__ void k_bsum(const int* __restrict__ degi_in, const int* __restrict__ degi_out,
                       int* __restrict__ bsum,
                       float* __restrict__ dso, float* __restrict__ dsi){
  __shared__ int wsum[16];
  int tid = threadIdx.x, lane = tid & 63, wv = tid >> 6;
  int i = blockIdx.x*1024 + tid;
  int v = (i < NN) ? degi_in[i] : 0;
  if(i < NN){
    dso[i] = rsqrtf((float)max(degi_out[i],1));
    dsi[i] = rsqrtf((float)max(v,1));
  }
  int r = v;
  for(int off=1; off<64; off<<=1) r += __shfl_xor(r, off);
  if(lane==0) wsum[wv] = r;
  __syncthreads();
  if(tid < 16){
    int t = wsum[tid];
    for(int off=1; off<16; off<<=1) t += __shfl_xor(t, off);
    if(tid==0) bsum[blockIdx.x] = t;
  }
}

/* exclusive scan of NSB block sums (single wave) */
__global__ void k_bscan(const int* __restrict__ bsum, int* __restrict__ boff){
  int lane = threadIdx.x;
  int v = (lane < NSB) ? bsum[lane] : 0;
  int sc = v;
  for(int off=1; off<64; off<<=1){
    int t = __shfl_up(sc, off);
    if(lane >= off) sc += t;
  }
  if(lane < NSB) boff[lane] = sc - v;
}

/* intra-block exclusive scan + block offset -> rowptr, cursor */
__global__ void k_scatter(const int* __restrict__ cnt, const int* __restrict__ boff,
                          int* __restrict__ rowptr, int* __restrict__ cursor){
  __shared__ int wsum[16];
  int tid = threadIdx.x, lane = tid & 63, wv = tid >> 6;
  int i = blockIdx.x*1024 + tid;
  int v = (i < NN) ? cnt[i] : 0;
  int sc = v;
  for(int off=1; off<64; off<<=1){
    int t = __shfl_up(sc, off);
    if(lane >= off) sc += t;
  }
  if(lane==63) wsum[wv] = sc;
  __syncthreads();
  if(wv==0){
    int t = (lane<16) ? wsum[lane] : 0;
    for(int off=1; off<16; off<<=1){
      int u = __shfl_up(t, off);
      if(lane >= off) t += u;
    }
    if(lane<16) wsum[lane] = t;
  }
  __syncthreads();
  int woff = (wv==0) ? 0 : wsum[wv-1];
  int ex = boff[blockIdx.x] + woff + sc - v;
  if(i < NN){ rowptr[i] = ex; cursor[i] = ex; }
  if(blockIdx.x==0 && tid==0) rowptr[NN] = NE;
}

__global__ void k_fill(const int* __restrict__ ei, int* __restrict__ cursor,
                       int* __restrict__ eidx){
  int e = blockIdx.x*256 + threadIdx.x;
  if(e < NE){
    int c = ei[NE + e];
    int p = atomicAdd(&cursor[c], 1);
    eidx[p] = ei[e];
  }
}

/* merged: blocks [0,768): W->Wt bf16 transpose; blocks [768,...): hs = x*dso */
__global__ void k_convprep(const float* __restrict__ W0, const float* __restrict__ W1,
                           const float* __restrict__ W2, unsigned short* __restrict__ Wt,
                           const float* __restrict__ x, const float* __restrict__ dso,
                           unsigned short* __restrict__ hs){
  if(blockIdx.x < 768){
    int t = blockIdx.x*256 + threadIdx.x;   /* 3*65536 */
    int l = t >> 16, r = t & 65535;
    int k = r >> 8, n = r & 255;
    const float* W = (l==0) ? W0 : (l==1) ? W1 : W2;
    Wt[(size_t)l*65536 + n*256 + k] = f2bf(W[k*256 + n]);
  } else {
    int t = (blockIdx.x - 768)*256 + threadIdx.x;   /* NN*64 */
    int row = t >> 6, c4 = (t & 63) << 2;
    if(row < NN){
      float s = dso[row];
      float4 v = *(const float4*)(x + (size_t)row*256 + c4);
      ushort4 o;
      o.x = f2bf(v.x*s); o.y = f2bf(v.y*s); o.z = f2bf(v.z*s); o.w = f2bf(v.w*s);
      *(ushort4*)(hs + (size_t)row*256 + c4) = o;
    }
  }
}

/* one node per HALF-WAVE (32 lanes, 8 elems/lane = full 256-col row).
   Index broadcast via shfl(width=32); 8 independent 16B gathers in flight.
   NORM=1: gather source = raw prev-layer out (bf16); apply
   relu(fma(v,cs,ch)) * dso[src] on the fly (fused BatchNorm+ReLU+scale). */
template<int NORM>
__global__ void k_agg(const unsigned short* __restrict__ src, const int* __restrict__ rowptr,
                      const int* __restrict__ eidx,
                      const float* __restrict__ cs, const float* __restrict__ ch,
                      const float* __restrict__ dso,
                      unsigned short* __restrict__ agg){
  int node = blockIdx.x*8 + (threadIdx.x >> 5);
  int l32 = threadIdx.x & 31;
  float csr[8], chr[8];
  if(NORM){
    #pragma unroll
    for(int k2=0;k2<8;k2++){ csr[k2] = cs[l32*8+k2]; chr[k2] = ch[l32*8+k2]; }
  }
  float a[8] = {0.f,0.f,0.f,0.f,0.f,0.f,0.f,0.f};
  int s = 0, e = 0;
  if(node < NN){ s = rowptr[node]; e = rowptr[node+1]; }
  int deg = e - s;
  for(int base=0; base<deg; base+=32){
    int cnt = min(deg - base, 32);
    int myidx = (base + l32 < deg) ? eidx[s + base + l32] : 0;
    for(int g=0; g<cnt; g+=8){
      int si[8];
      #pragma unroll
      for(int i=0;i<8;i++) si[i] = __shfl(myidx, g+i, 32);
      u16x8 v[8];
      #pragma unroll
      for(int i=0;i<8;i++) v[i] = *(const u16x8*)(src + (size_t)si[i]*256 + l32*8);
      float d[8];
      if(NORM){
        #pragma unroll
        for(int i=0;i<8;i++) d[i] = dso[si[i]];
      }
      #pragma unroll
      for(int i=0;i<8;i++){
        if(g+i < cnt){
          #pragma unroll
          for(int k2=0;k2<8;k2++){
            float y = bf2f(v[i][k2]);
            if(NORM) y = fmaxf(fmaf(y, csr[k2], chr[k2]), 0.f) * d[i];
            a[k2] += y;
          }
        }
      }
    }
  }
  if(node < MPAD){
    u16x8 o;
    #pragma unroll
    for(int k2=0;k2<8;k2++) o[k2] = f2bf(a[k2]);
    *(u16x8*)(agg + (size_t)node*256 + l32*8) = o;
  }
}

/* GEMM 64x128 tile, BK=64, double-buffered 48KB LDS, 2-phase:
   STAGE(next) issued BEFORE compute(cur); __syncthreads()'s implicit
   vmcnt-drain is the only barrier per K-step. grid (2, 782).
   Bias/dsi/residual loads hoisted before the K-loop (in flight under MFMA).
   out[m][n] = (sum_k A[m][k]*W[k][n] + b[n]) * dsi[m] (+ residual).
   RESMODE: 0=none, 1=f32 residual, 3=bf16 prev-out + fused norm+relu residual.
   STATS: per-(m-block,wm) column partials in TRANSPOSED [col][wid] layout. */
template<int RESMODE, int STATS, int OUTBF>
__global__ __launch_bounds__(256) void k_gemm(
    const unsigned short* __restrict__ A,    /* [MPAD][256] bf16 */
    const unsigned short* __restrict__ Bt,   /* [256][256] bf16 = W^T */
    const float* __restrict__ bias,
    const float* __restrict__ dsi,
    const float* __restrict__ resf,
    const unsigned short* __restrict__ resb,
    const float* __restrict__ rcs, const float* __restrict__ rch,
    void* __restrict__ outp,
    float* __restrict__ ps, float* __restrict__ pq)
{
  __shared__ __align__(16) unsigned char smem[49152];   /* 2 x (A 8KB + B 16KB) */
  const int tid = threadIdx.x;
  const int w = tid >> 6, lane = tid & 63;
  const int m0 = blockIdx.y * 64, n0 = blockIdx.x * 128;
  const int wm = w & 1, wn = w >> 1;

  /* ---- hoisted epilogue operands (fly under the K-loop) ---- */
  const int colb = n0 + wn*64 + (lane & 15);
  float bs[4], rcsv[4], rchv[4];
  #pragma unroll
  for(int nf=0; nf<4; ++nf) bs[nf] = bias[colb + nf*16];
  if(RESMODE==3){
    #pragma unroll
    for(int nf=0; nf<4; ++nf){ rcsv[nf] = rcs[colb + nf*16]; rchv[nf] = rch[colb + nf*16]; }
  }
  float dv[8];
  float rvf[32];
  unsigned short rvb[32];
  #pragma unroll
  for(int mf=0; mf<2; ++mf){
    const int growb = m0 + wm*32 + mf*16 + ((lane>>4)<<2);
    #pragma unroll
    for(int j=0; j<4; ++j){
      const int grow = growb + j;
      const bool ok = grow < NN;
      dv[mf*4+j] = ok ? dsi[grow] : 0.f;
      if(RESMODE){
        const size_t rb = (size_t)grow * 256;
        #pragma unroll
        for(int nf=0; nf<4; ++nf){
          if(RESMODE==1) rvf[mf*16+j*4+nf] = ok ? resf[rb + colb + nf*16] : 0.f;
          else           rvb[mf*16+j*4+nf] = ok ? resb[rb + colb + nf*16] : (unsigned short)0;
        }
      }
    }
  }

  f32x4 acc[2][4];
  #pragma unroll
  for(int i=0;i<2;i++)
    #pragma unroll
    for(int j=0;j<4;j++) acc[i][j] = (f32x4){0.f,0.f,0.f,0.f};

  const char* Ab = (const char*)A;
  const char* Bb = (const char*)Bt;

  auto STAGE = [&](int buf, int kt){
    unsigned char* sA = smem + buf*24576;
    unsigned char* sB = sA + 8192;
    #pragma unroll
    for(int it=0; it<2; ++it){
      const int flat = it*256 + tid;
      const int row = flat >> 3, ch_ = flat & 7;
      const int sw = ch_ ^ (row & 7);
      gl_lds16(Ab + (size_t)(m0+row)*512 + kt*128 + sw*16,
               sA + (size_t)(it*256 + w*64)*16);
    }
    #pragma unroll
    for(int it=0; it<4; ++it){
      const int flat = it*256 + tid;
      const int row = flat >> 3, ch_ = flat & 7;
      const int sw = ch_ ^ (row & 7);
      gl_lds16(Bb + (size_t)(n0+row)*512 + kt*128 + sw*16,
               sB + (size_t)(it*256 + w*64)*16);
    }
  };

  STAGE(0, 0);
  __syncthreads();   /* implicit vmcnt(0) drain */

  for(int kt=0; kt<4; ++kt){
    const int cur = kt & 1;
    if(kt < 3) STAGE(cur^1, kt+1);        /* loads fly during MFMA below */
    unsigned char* sA = smem + cur*24576;
    unsigned char* sB = sA + 8192;
    #pragma unroll
    for(int ks=0; ks<2; ++ks){
      const int ca = ks*4 + (lane >> 4);
      bf16x8 av[2], bv[4];
      #pragma unroll
      for(int f=0; f<2; ++f){
        const int ra = wm*32 + f*16 + (lane & 15);
        av[f] = *(const bf16x8*)(sA + ra*128 + ((ca ^ (ra & 7)) << 4));
      }
      #pragma unroll
      for(int f=0; f<4; ++f){
        const int rb = wn*64 + f*16 + (lane & 15);
        bv[f] = *(const bf16x8*)(sB + rb*128 + ((ca ^ (rb & 7)) << 4));
      }
      #pragma unroll
      for(int mf=0; mf<2; ++mf)
        #pragma unroll
        for(int nf=0; nf<4; ++nf)
          acc[mf][nf] = __builtin_amdgcn_mfma_f32_16x16x32_bf16(av[mf], bv[nf], acc[mf][nf], 0,0,0);
    }
    __syncthreads();   /* drains next-tile loads (overlapped with MFMA) */
  }

  /* epilogue: C row = (lane>>4)*4+j, col = lane&15 (per 16x16 frag) */
  float s[4] = {0.f,0.f,0.f,0.f}, q[4] = {0.f,0.f,0.f,0.f};
  #pragma unroll
  for(int mf=0; mf<2; ++mf){
    const int growb = m0 + wm*32 + mf*16 + ((lane>>4)<<2);
    #pragma unroll
    for(int j=0; j<4; ++j){
      const int grow = growb + j;
      if(grow < NN){
        const float d = dv[mf*4+j];
        const size_t rb = (size_t)grow * 256;
        #pragma unroll
        for(int nf=0; nf<4; ++nf){
          float v = (acc[mf][nf][j] + bs[nf]) * d;
          if(RESMODE==1) v += rvf[mf*16+j*4+nf];
          if(RESMODE==3) v += fmaxf(fmaf(bf2f(rvb[mf*16+j*4+nf]), rcsv[nf], rchv[nf]), 0.f);
          if(OUTBF) ((unsigned short*)outp)[rb + colb + nf*16] = f2bf(v);
          else      ((float*)outp)[rb + colb + nf*16] = v;
          if(STATS){ s[nf] += v; q[nf] += v*v; }
        }
      }
    }
  }
  if(STATS){
    const int wid = blockIdx.y*2 + wm;
    #pragma unroll
    for(int nf=0; nf<4; ++nf){
      float sv = s[nf], qv = q[nf];
      sv += __shfl_xor(sv, 16); sv += __shfl_xor(sv, 32);
      qv += __shfl_xor(qv, 16); qv += __shfl_xor(qv, 32);
      if(lane < 16){
        ps[(size_t)(colb + nf*16)*NWID + wid] = sv;
        pq[(size_t)(colb + nf*16)*NWID + wid] = qv;
      }
    }
  }
}

/* one block per column: reduce NWID partials (coalesced), finalize cs/ch */
__global__ void k_statsall(const float* __restrict__ ps, const float* __restrict__ pq,
                           const float* __restrict__ g, const float* __restrict__ be,
                           float* __restrict__ cs, float* __restrict__ ch){
  __shared__ float rs[4], rq[4];
  int c = blockIdx.x, t = threadIdx.x;
  float s = 0.f, q = 0.f;
  for(int r = t; r < NWID; r += 256){
    s += ps[(size_t)c*NWID + r];
    q += pq[(size_t)c*NWID + r];
  }
  for(int off=1; off<64; off<<=1){ s += __shfl_xor(s, off); q += __shfl_xor(q, off); }
  if((t & 63) == 0){ rs[t>>6] = s; rq[t>>6] = q; }
  __syncthreads();
  if(t == 0){
    float S = rs[0]+rs[1]+rs[2]+rs[3], Q = rq[0]+rq[1]+rq[2]+rq[3];
    float mu  = S * (1.0f/NN);
    float var = fmaxf(Q * (1.0f/NN) - mu*mu, 0.f);
    float inv = rsqrtf(var + EPSV);
    float sc = g[c] * inv;
    cs[c] = sc;
    ch[c] = be[c] - mu * sc;
  }
}

extern "C" void kernel_launch(void* const* d_in, const int* in_sizes, int n_in,
                              void* d_out, int out_size, void* d_ws, size_t ws_size,
                              hipStream_t stream){
  (void)in_sizes; (void)n_in; (void)out_size;
  const float* x  = (const float*)d_in[0];
  const int*   ei = (const int*)d_in[1];
  const float* Wl[3]  = {(const float*)d_in[2], (const float*)d_in[6], (const float*)d_in[10]};
  const float* bl[3]  = {(const float*)d_in[3], (const float*)d_in[7], (const float*)d_in[11]};
  const float* gl[2]  = {(const float*)d_in[4], (const float*)d_in[8]};
  const float* bel[2] = {(const float*)d_in[5], (const float*)d_in[9]};

  char* base = (char*)d_ws;
  size_t off = 0;
  auto alloc = [&](size_t bytes)->char* {
    char* r = base + off;
    off = (off + bytes + 511) & ~(size_t)511;
    return r;
  };
  int* degi_out = (int*)alloc((size_t)2*NN*4);
  int* degi_in  = degi_out + NN;
  float* dso    = (float*)alloc((size_t)NN*4);
  float* dsi    = (float*)alloc((size_t)NN*4);
  int* rowptr   = (int*)alloc((size_t)(NN+1)*4);
  int* cursor   = (int*)alloc((size_t)NN*4);
  int* eidx     = (int*)alloc((size_t)NE*4);
  int* bsum     = (int*)alloc((size_t)NSB*4);
  int* boff     = (int*)alloc((size_t)NSB*4);
  unsigned short* Wt = (unsigned short*)alloc((size_t)3*65536*2);
  float* ps     = (float*)alloc((size_t)NWID*256*4);
  float* pq     = (float*)alloc((size_t)NWID*256*4);
  float* cs0    = (float*)alloc(1024);
  float* ch0    = (float*)alloc(1024);
  float* cs1    = (float*)alloc(1024);
  float* ch1    = (float*)alloc(1024);
  unsigned short* hs  = (unsigned short*)alloc((size_t)MPAD*256*2);
  unsigned short* agg = (unsigned short*)alloc((size_t)MPAD*256*2);
  unsigned short* ob0 = (unsigned short*)alloc((size_t)MPAD*256*2);
  unsigned short* ob1 = (unsigned short*)alloc((size_t)MPAD*256*2);
  if(off > ws_size) return;   /* workspace too small: fail visibly */

  /* graph prep (layer-invariant) */
  (void)hipMemsetAsync(degi_out, 0, (size_t)2*NN*4, stream);
  k_degree<<<(NE+255)/256, 256, 0, stream>>>(ei, degi_out, degi_in);
  k_bsum<<<NSB, 1024, 0, stream>>>(degi_in, degi_out, bsum, dso, dsi);
  k_bscan<<<1, 64, 0, stream>>>(bsum, boff);
  k_scatter<<<NSB, 1024, 0, stream>>>(degi_in, boff, rowptr, cursor);
  k_fill<<<(NE+255)/256, 256, 0, stream>>>(ei, cursor, eidx);
  k_convprep<<<768 + (NN*64+255)/256, 256, 0, stream>>>(Wl[0], Wl[1], Wl[2], Wt, x, dso, hs);

  dim3 gg(2, 782);
  /* layer 0: gather hs, residual = x (f32), stats -> ob0 */
  k_agg<0><<<MPAD/8, 256, 0, stream>>>(hs, rowptr, eidx, nullptr, nullptr, nullptr, agg);
  k_gemm<1,1,1><<<gg, 256, 0, stream>>>(agg, Wt, bl[0], dsi, x, nullptr, nullptr, nullptr,
                                        ob0, ps, pq);
  k_statsall<<<256, 256, 0, stream>>>(ps, pq, gl[0], bel[0], cs0, ch0);
  /* layer 1: gather = norm0(ob0) on the fly; residual = norm0(ob0) in epilogue */
  k_agg<1><<<MPAD/8, 256, 0, stream>>>(ob0, rowptr, eidx, cs0, ch0, dso, agg);
  k_gemm<3,1,1><<<gg, 256, 0, stream>>>(agg, Wt + 65536, bl[1], dsi, nullptr, ob0, cs0, ch0,
                                        ob1, ps, pq);
  k_statsall<<<256, 256, 0, stream>>>(ps, pq, gl[1], bel[1], cs1, ch1);
  /* layer 2: gather = norm1(ob1) on the fly; no residual, f32 out */
  k_agg<1><<<MPAD/8, 256, 0, stream>>>(ob1, rowptr, eidx, cs1, ch1, dso, agg);
  k_gemm<0,0,0><<<gg, 256, 0, stream>>>(agg, Wt + 2*65536, bl[2], dsi, nullptr, nullptr,
                                        nullptr, nullptr, d_out, nullptr, nullptr);
}